// Round 4
// baseline (6408.244 us; speedup 1.0000x reference)
//
#include <hip/hip_runtime.h>

#define NB 64
#define NC 32
#define NH 16
#define NW 16
#define NE 4096
#define NTOT (NB*NC*NH*NW)   // 524288
#define IDXW 341             // 1+4+16+64+256

__device__ __forceinline__ double cubicw(double x) {
  const double A = -0.75;
  x = fabs(x);
  if (x <= 1.0) return ((A + 2.0) * x - (A + 3.0)) * x * x + 1.0;
  if (x < 2.0)  return A * (((x - 5.0) * x + 8.0) * x - 4.0);
  return 0.0;
}

__global__ void k_init(const float* __restrict__ z, double* __restrict__ z_res,
                       double* __restrict__ z_hat_d, double* __restrict__ loss_d) {
  int i = blockIdx.x * 256 + threadIdx.x;
  if (i < NTOT) { z_res[i] = (double)z[i]; z_hat_d[i] = 0.0; }
  if (i == 0) *loss_d = 0.0;
}

__global__ void k_embsq(const float* __restrict__ emb, double* __restrict__ emb_sq) {
  int e = blockIdx.x * 256 + threadIdx.x;
  if (e >= NE) return;
  const float4* p = (const float4*)(emb + e * NC);
  double s = 0.0;
  #pragma unroll
  for (int j = 0; j < 8; j++) {
    float4 v = p[j];
    s += (double)v.x * v.x + (double)v.y * v.y + (double)v.z * v.z + (double)v.w * v.w;
  }
  emb_sq[e] = s;
}

// area downsample: r[b,c,y,x] = mean of f x f block of z_res (fp64)
__global__ void k_pool(const double* __restrict__ z_res, double* __restrict__ r,
                       int ph, int f) {
  int i = blockIdx.x * 256 + threadIdx.x;
  int n = NB * NC * ph * ph;
  if (i >= n) return;
  int x = i % ph; int y = (i / ph) % ph; int bc = i / (ph * ph);
  const double* base = z_res + (bc * NH + y * f) * NW + x * f;
  double s = 0.0;
  for (int dy = 0; dy < f; dy++)
    for (int dx = 0; dx < f; dx++) s += base[dy * NW + dx];
  r[i] = s / (double)(f * f);
}

// nearest-codebook search, 8 rows per block, fp64 distances
#define ROWS 8
__global__ void k_argmin(const double* __restrict__ r, const float* __restrict__ emb,
                         const double* __restrict__ emb_sq, int ph,
                         int* __restrict__ idx_ws, float* __restrict__ out_idx,
                         int idx_off) {
  __shared__ double rv[ROWS][NC];
  int tid = threadIdx.x;
  int row0 = blockIdx.x * ROWS;
  if (tid < ROWS * NC) {
    int j = tid / NC, c = tid % NC;
    int n = row0 + j;
    int x = n % ph, y = (n / ph) % ph, b = n / (ph * ph);
    rv[j][c] = r[((b * NC + c) * ph + y) * ph + x];
  }
  __syncthreads();
  double best[ROWS]; int bi[ROWS];
  #pragma unroll
  for (int j = 0; j < ROWS; j++) { best[j] = 1e300; bi[j] = 0; }
  for (int e = tid; e < NE; e += 256) {
    const float4* p = (const float4*)(emb + e * NC);
    double acc[ROWS];
    #pragma unroll
    for (int j = 0; j < ROWS; j++) acc[j] = 0.0;
    #pragma unroll
    for (int ch = 0; ch < 8; ch++) {
      float4 v = p[ch];
      double d0 = v.x, d1 = v.y, d2 = v.z, d3 = v.w;
      #pragma unroll
      for (int j = 0; j < ROWS; j++)
        acc[j] += rv[j][4*ch+0]*d0 + rv[j][4*ch+1]*d1 + rv[j][4*ch+2]*d2 + rv[j][4*ch+3]*d3;
    }
    double esq = emb_sq[e];
    #pragma unroll
    for (int j = 0; j < ROWS; j++) {
      double d = esq - 2.0 * acc[j];
      if (d < best[j]) { best[j] = d; bi[j] = e; }  // ascending e per thread: strict < keeps first
    }
  }
  __shared__ double sd[256];
  __shared__ int sidx[256];
  for (int j = 0; j < ROWS; j++) {
    sd[tid] = best[j]; sidx[tid] = bi[j];
    __syncthreads();
    for (int s = 128; s > 0; s >>= 1) {
      if (tid < s) {
        double od = sd[tid + s]; int oi = sidx[tid + s];
        if (od < sd[tid] || (od == sd[tid] && oi < sidx[tid])) { sd[tid] = od; sidx[tid] = oi; }
      }
      __syncthreads();
    }
    if (tid == 0) {
      int n = row0 + j;
      int w = sidx[0];
      idx_ws[n] = w;
      int x = n % ph, y = (n / ph) % ph, b = n / (ph * ph);
      out_idx[b * IDXW + idx_off + y * ph + x] = (float)w;
    }
    __syncthreads();
  }
}

// q[b,c,y,x] = emb[idx[b,y,x], c]  (fp64 out)
__global__ void k_gather(const int* __restrict__ idx_ws, const float* __restrict__ emb,
                         double* __restrict__ q_out, int ph) {
  int i = blockIdx.x * 256 + threadIdx.x;
  int ntot = NB * NC * ph * ph;
  if (i >= ntot) return;
  int x = i % ph, y = (i / ph) % ph, c = (i / (ph * ph)) % NC, b = i / (ph * ph * NC);
  int n = (b * ph + y) * ph + x;
  q_out[i] = (double)emb[idx_ws[n] * NC + c];
}

// resize axis 2 (height): [B,C,ph,ph] -> [B,C,16,ph]  (fp64)
__global__ void k_bicubic_h(const double* __restrict__ in, double* __restrict__ out, int ph) {
  int i = blockIdx.x * 256 + threadIdx.x;
  int ntot = NB * NC * 16 * ph;
  if (i >= ntot) return;
  int x = i % ph; int oy = (i / ph) % 16; int bc = i / (ph * 16);
  double scale = (double)ph / 16.0;
  double src = ((double)oy + 0.5) * scale - 0.5;
  double fi = floor(src);
  int i0 = (int)fi;
  double frac = src - fi;
  double s = 0.0;
  #pragma unroll
  for (int k = 0; k < 4; k++) {
    int iy = min(max(i0 + k - 1, 0), ph - 1);
    s += cubicw(frac - (double)(k - 1)) * in[(bc * ph + iy) * ph + x];
  }
  out[i] = s;
}

// resize axis 3 (width): [B,C,16,ph] -> [B,C,16,16]  (fp64)
__global__ void k_bicubic_w(const double* __restrict__ in, double* __restrict__ out, int ph) {
  int i = blockIdx.x * 256 + threadIdx.x;
  if (i >= NTOT) return;
  int ox = i % 16; int row = i / 16;
  double scale = (double)ph / 16.0;
  double src = ((double)ox + 0.5) * scale - 0.5;
  double fi = floor(src);
  int i0 = (int)fi;
  double frac = src - fi;
  double s = 0.0;
  #pragma unroll
  for (int k = 0; k < 4; k++) {
    int ix = min(max(i0 + k - 1, 0), ph - 1);
    s += cubicw(frac - (double)(k - 1)) * in[row * ph + ix];
  }
  out[i] = s;
}

// Phi (0.5*x + 0.5*(conv3x3(x)+b)) + z_hat/z_res update + loss partial (all fp64)
__global__ void k_phi_update(const double* __restrict__ q, const float* __restrict__ w,
                             const float* __restrict__ bias, const float* __restrict__ z,
                             double* __restrict__ z_hat_d, double* __restrict__ z_res,
                             float* __restrict__ out_zhat, double* __restrict__ loss_d) {
  __shared__ double sq[16 * NH * NW];  // 32 KB
  int b = blockIdx.x >> 2;
  int part = blockIdx.x & 3;
  int tid = threadIdx.x;
  const double* qb = q + b * NC * NH * NW;
  double acc[8];
  #pragma unroll
  for (int k = 0; k < 8; k++) acc[k] = 0.0;
  for (int half = 0; half < 2; half++) {
    __syncthreads();
    for (int i = tid; i < 16 * NH * NW; i += 256) sq[i] = qb[half * 16 * NH * NW + i];
    __syncthreads();
    for (int k = 0; k < 8; k++) {
      int i = part * 2048 + k * 256 + tid;
      int x = i % NW, y = (i / NW) % NH, co = i / (NH * NW);
      const float* wc = w + (co * NC + half * 16) * 9;
      double a = acc[k];
      for (int ci = 0; ci < 16; ci++) {
        const double* sp = sq + ci * NH * NW;
        const float* wp = wc + ci * 9;
        #pragma unroll
        for (int ky = 0; ky < 3; ky++) {
          int yy = y + ky - 1;
          if (yy < 0 || yy >= NH) continue;
          #pragma unroll
          for (int kx = 0; kx < 3; kx++) {
            int xx = x + kx - 1;
            if (xx < 0 || xx >= NW) continue;
            a += sp[yy * NW + xx] * (double)wp[ky * 3 + kx];
          }
        }
      }
      acc[k] = a;
    }
  }
  double lsum = 0.0;
  #pragma unroll
  for (int k = 0; k < 8; k++) {
    int i = part * 2048 + k * 256 + tid;
    int co = i / (NH * NW);
    int gi = b * NC * NH * NW + i;
    double val = qb[i] * 0.5 + (acc[k] + (double)bias[co]) * 0.5;
    double zh = z_hat_d[gi] + val;
    z_hat_d[gi] = zh;
    out_zhat[gi] = (float)zh;
    z_res[gi] -= val;
    double df = zh - (double)z[gi];
    lsum += df * df;
  }
  __shared__ double red[256];
  red[tid] = lsum; __syncthreads();
  for (int s = 128; s > 0; s >>= 1) {
    if (tid < s) red[tid] += red[tid + s];
    __syncthreads();
  }
  if (tid == 0) atomicAdd(loss_d, red[0]);
}

__global__ void k_finalize(const double* __restrict__ loss_d, float* __restrict__ out_loss) {
  // loss = sum_sq_total * (1+BETA) / (K * NTOT)
  *out_loss = (float)(*loss_d * (1.25 / (5.0 * (double)NTOT)));
}

extern "C" void kernel_launch(void* const* d_in, const int* in_sizes, int n_in,
                              void* d_out, int out_size, void* d_ws, size_t ws_size,
                              hipStream_t stream) {
  const float* z     = (const float*)d_in[0];   // [64,32,16,16]
  const float* emb   = (const float*)d_in[1];   // [4096,32]
  const float* phi_w = (const float*)d_in[2];   // [4,32,32,3,3]
  const float* phi_b = (const float*)d_in[3];   // [4,32]

  float* out      = (float*)d_out;
  float* out_zhat = out;            // z_hat_st == z_hat numerically
  float* out_loss = out + NTOT;
  float* out_idx  = out + NTOT + 1; // [64,341] as floats

  double* ws      = (double*)d_ws;
  double* z_res   = ws;                    // NTOT
  double* z_hat_d = z_res + NTOT;          // NTOT
  double* q_small = z_hat_d + NTOT;        // NTOT
  double* t1      = q_small + NTOT;        // NB*NC*16*8 = 262144 max
  double* q       = t1 + 262144;           // NTOT
  double* r       = q + NTOT;              // NTOT
  double* emb_sq  = r + NTOT;              // NE
  double* loss_d  = emb_sq + NE;           // 1
  int* idx_ws     = (int*)(loss_d + 1);    // NB*256

  k_init<<<(NTOT + 255) / 256, 256, 0, stream>>>(z, z_res, z_hat_d, loss_d);
  k_embsq<<<(NE + 255) / 256, 256, 0, stream>>>(emb, emb_sq);

  const int phs[5]  = {1, 2, 4, 8, 16};
  // Phi tick selection: ticks = np.linspace(1/12, 11/12, 4) in float64.
  // si=2 is an EXACT tie in real arithmetic (5/36 both sides), but f64
  // linspace rounding makes |ticks[2]-0.5| smaller by 2 ulps -> pi=2.
  // (verified by exact mantissa-integer arithmetic; NOT first-on-tie pi=1)
  const int pis[5]  = {0, 1, 2, 2, 3};
  const int offs[5] = {0, 1, 5, 21, 85};

  for (int si = 0; si < 5; si++) {
    int ph = phs[si];
    int nrows = NB * ph * ph;
    int nel = NB * NC * ph * ph;
    const double* rptr;
    if (si != 4) {
      int f = NH / ph;
      k_pool<<<(nel + 255) / 256, 256, 0, stream>>>(z_res, r, ph, f);
      rptr = r;
    } else {
      rptr = z_res;  // full-res residual, [B,C,16,16] layout matches ph=16
    }
    k_argmin<<<nrows / ROWS, 256, 0, stream>>>(rptr, emb, emb_sq, ph,
                                               idx_ws, out_idx, offs[si]);
    double* qdst = (si != 4) ? q_small : q;
    k_gather<<<(nel + 255) / 256, 256, 0, stream>>>(idx_ws, emb, qdst, ph);
    if (si != 4) {
      int nh = NB * NC * 16 * ph;
      k_bicubic_h<<<(nh + 255) / 256, 256, 0, stream>>>(q_small, t1, ph);
      k_bicubic_w<<<(NTOT + 255) / 256, 256, 0, stream>>>(t1, q, ph);
    }
    k_phi_update<<<NB * 4, 256, 0, stream>>>(q, phi_w + pis[si] * NC * NC * 9,
                                             phi_b + pis[si] * NC,
                                             z, z_hat_d, z_res, out_zhat, loss_d);
  }
  k_finalize<<<1, 1, 0, stream>>>(loss_d, out_loss);
}

// Round 5
// 1082.488 us; speedup vs baseline: 5.9199x; 5.9199x over previous
//
#include <hip/hip_runtime.h>

#define NB 64
#define NC 32
#define NH 16
#define NW 16
#define NE 4096
#define NTOT (NB*NC*NH*NW)   // 524288
#define IDXW 341             // 1+4+16+64+256

__device__ __forceinline__ double cubicw(double x) {
  const double A = -0.75;
  x = fabs(x);
  if (x <= 1.0) return ((A + 2.0) * x - (A + 3.0)) * x * x + 1.0;
  if (x < 2.0)  return A * (((x - 5.0) * x + 8.0) * x - 4.0);
  return 0.0;
}

__global__ void k_init(const float* __restrict__ z, double* __restrict__ z_res,
                       double* __restrict__ z_hat_d, double* __restrict__ loss_d) {
  int i = blockIdx.x * 256 + threadIdx.x;
  if (i < NTOT) { z_res[i] = (double)z[i]; z_hat_d[i] = 0.0; }
  if (i == 0) *loss_d = 0.0;
}

__global__ void k_embsq(const float* __restrict__ emb, double* __restrict__ emb_sq) {
  int e = blockIdx.x * 256 + threadIdx.x;
  if (e >= NE) return;
  const float4* p = (const float4*)(emb + e * NC);
  double s = 0.0;
  #pragma unroll
  for (int j = 0; j < 8; j++) {
    float4 v = p[j];
    s += (double)v.x * v.x + (double)v.y * v.y + (double)v.z * v.z + (double)v.w * v.w;
  }
  emb_sq[e] = s;
}

// emb [4096][32] -> emb_t [32][4096], LDS-tiled so both sides coalesce.
// 64 blocks x 256 threads; each block does 64 entries x 32 channels.
__global__ void k_transpose(const float* __restrict__ emb, float* __restrict__ emb_t) {
  __shared__ float tile[64][33];  // +1 pad: conflict-free transposed reads
  int tid = threadIdx.x;
  int e0 = blockIdx.x * 64;
  #pragma unroll
  for (int i2 = 0; i2 < 8; i2++) {
    int i = i2 * 256 + tid;          // 0..2047
    int el = i >> 5, c = i & 31;     // read coalesced: emb[(e0+el)*32 + c]
    tile[el][c] = emb[(e0 + el) * NC + c];
  }
  __syncthreads();
  #pragma unroll
  for (int i2 = 0; i2 < 8; i2++) {
    int i = i2 * 256 + tid;
    int c = i >> 6, ep = i & 63;     // write coalesced: emb_t[c*4096 + e0+ep]
    emb_t[c * NE + e0 + ep] = tile[ep][c];
  }
}

// area downsample: r[b,c,y,x] = mean of f x f block of z_res (fp64)
__global__ void k_pool(const double* __restrict__ z_res, double* __restrict__ r,
                       int ph, int f) {
  int i = blockIdx.x * 256 + threadIdx.x;
  int n = NB * NC * ph * ph;
  if (i >= n) return;
  int x = i % ph; int y = (i / ph) % ph; int bc = i / (ph * ph);
  const double* base = z_res + (bc * NH + y * f) * NW + x * f;
  double s = 0.0;
  for (int dy = 0; dy < f; dy++)
    for (int dx = 0; dx < f; dx++) s += base[dy * NW + dx];
  r[i] = s / (double)(f * f);
}

// nearest-codebook search v2: transposed codebook, coalesced float4 entry loads.
// 8 rows/block; each thread owns 4 consecutive entries per chunk; fp64 distances.
#define ROWS 8
#define EV 4
__global__ void k_argmin(const double* __restrict__ r, const float* __restrict__ emb_t,
                         const double* __restrict__ emb_sq, int ph,
                         int* __restrict__ idx_ws, float* __restrict__ out_idx,
                         int idx_off) {
  __shared__ double rv[ROWS][NC];   // 2 KB, broadcast-read (wave-uniform addr)
  __shared__ double wd[4][ROWS];
  __shared__ int    wi[4][ROWS];
  int tid = threadIdx.x;
  int row0 = blockIdx.x * ROWS;
  {
    int j = tid >> 5, c = tid & 31;   // 256 threads = 8*32 exactly
    int n = row0 + j;
    int x = n % ph, y = (n / ph) % ph, b = n / (ph * ph);
    rv[j][c] = r[((b * NC + c) * ph + y) * ph + x];
  }
  __syncthreads();
  double best[ROWS]; int bidx[ROWS];
  #pragma unroll
  for (int j = 0; j < ROWS; j++) { best[j] = 1e300; bidx[j] = 0; }
  for (int it = 0; it < NE / (256 * EV); ++it) {   // 4 chunks
    int e0 = it * (256 * EV) + tid * EV;
    double acc[ROWS][EV];
    #pragma unroll
    for (int j = 0; j < ROWS; j++)
      #pragma unroll
      for (int v = 0; v < EV; v++) acc[j][v] = 0.0;
    #pragma unroll 4
    for (int k = 0; k < NC; k++) {
      float4 e4 = *(const float4*)(emb_t + k * NE + e0);  // coalesced 16B/lane
      double d0 = e4.x, d1 = e4.y, d2 = e4.z, d3 = e4.w;
      #pragma unroll
      for (int j = 0; j < ROWS; j++) {
        double rj = rv[j][k];
        acc[j][0] += rj * d0; acc[j][1] += rj * d1;
        acc[j][2] += rj * d2; acc[j][3] += rj * d3;
      }
    }
    #pragma unroll
    for (int v = 0; v < EV; v++) {     // v ascending: lowest e kept on ties
      double esq = emb_sq[e0 + v];
      #pragma unroll
      for (int j = 0; j < ROWS; j++) {
        double d = esq - 2.0 * acc[j][v];
        if (d < best[j]) { best[j] = d; bidx[j] = e0 + v; }
      }
    }
  }
  // wave butterfly merge (min dist, tie -> lower index)
  #pragma unroll
  for (int j = 0; j < ROWS; j++) {
    double d = best[j]; int bi2 = bidx[j];
    #pragma unroll
    for (int off = 32; off >= 1; off >>= 1) {
      double od = __shfl_xor(d, off, 64);
      int oi = __shfl_xor(bi2, off, 64);
      if (od < d || (od == d && oi < bi2)) { d = od; bi2 = oi; }
    }
    best[j] = d; bidx[j] = bi2;
  }
  int wave = tid >> 6, lane = tid & 63;
  if (lane == 0) {
    #pragma unroll
    for (int j = 0; j < ROWS; j++) { wd[wave][j] = best[j]; wi[wave][j] = bidx[j]; }
  }
  __syncthreads();
  if (tid < ROWS) {
    double d = wd[0][tid]; int bi2 = wi[0][tid];
    #pragma unroll
    for (int w2 = 1; w2 < 4; w2++) {
      double od = wd[w2][tid]; int oi = wi[w2][tid];
      if (od < d || (od == d && oi < bi2)) { d = od; bi2 = oi; }
    }
    int n = row0 + tid;
    idx_ws[n] = bi2;
    int x = n % ph, y = (n / ph) % ph, b = n / (ph * ph);
    out_idx[b * IDXW + idx_off + y * ph + x] = (float)bi2;
  }
}

// q[b,c,y,x] = emb[idx[b,y,x], c]  (fp64 out)
__global__ void k_gather(const int* __restrict__ idx_ws, const float* __restrict__ emb,
                         double* __restrict__ q_out, int ph) {
  int i = blockIdx.x * 256 + threadIdx.x;
  int ntot = NB * NC * ph * ph;
  if (i >= ntot) return;
  int x = i % ph, y = (i / ph) % ph, c = (i / (ph * ph)) % NC, b = i / (ph * ph * NC);
  int n = (b * ph + y) * ph + x;
  q_out[i] = (double)emb[idx_ws[n] * NC + c];
}

// resize axis 2 (height): [B,C,ph,ph] -> [B,C,16,ph]  (fp64)
__global__ void k_bicubic_h(const double* __restrict__ in, double* __restrict__ out, int ph) {
  int i = blockIdx.x * 256 + threadIdx.x;
  int ntot = NB * NC * 16 * ph;
  if (i >= ntot) return;
  int x = i % ph; int oy = (i / ph) % 16; int bc = i / (ph * 16);
  double scale = (double)ph / 16.0;
  double src = ((double)oy + 0.5) * scale - 0.5;
  double fi = floor(src);
  int i0 = (int)fi;
  double frac = src - fi;
  double s = 0.0;
  #pragma unroll
  for (int k = 0; k < 4; k++) {
    int iy = min(max(i0 + k - 1, 0), ph - 1);
    s += cubicw(frac - (double)(k - 1)) * in[(bc * ph + iy) * ph + x];
  }
  out[i] = s;
}

// resize axis 3 (width): [B,C,16,ph] -> [B,C,16,16]  (fp64)
__global__ void k_bicubic_w(const double* __restrict__ in, double* __restrict__ out, int ph) {
  int i = blockIdx.x * 256 + threadIdx.x;
  if (i >= NTOT) return;
  int ox = i % 16; int row = i / 16;
  double scale = (double)ph / 16.0;
  double src = ((double)ox + 0.5) * scale - 0.5;
  double fi = floor(src);
  int i0 = (int)fi;
  double frac = src - fi;
  double s = 0.0;
  #pragma unroll
  for (int k = 0; k < 4; k++) {
    int ix = min(max(i0 + k - 1, 0), ph - 1);
    s += cubicw(frac - (double)(k - 1)) * in[row * ph + ix];
  }
  out[i] = s;
}

// Phi v2: grid = 64 images x 8 co-groups (4 co each), 256 threads = 1/pixel.
// Full image in 64 KB LDS; one 9-pt window read feeds 4 output channels.
__global__ __launch_bounds__(256) void k_phi_update(
    const double* __restrict__ q, const float* __restrict__ w,
    const float* __restrict__ bias, const float* __restrict__ z,
    double* __restrict__ z_hat_d, double* __restrict__ z_res,
    float* __restrict__ out_zhat, double* __restrict__ loss_d) {
  __shared__ double simg[NC * NH * NW];  // exactly 64 KB
  int b = blockIdx.x >> 3;
  int co0 = (blockIdx.x & 7) * 4;
  int tid = threadIdx.x;
  const double* qb = q + b * NC * NH * NW;
  for (int i = tid; i < NC * NH * NW; i += 256) simg[i] = qb[i];
  __syncthreads();
  int x = tid & 15, y = tid >> 4;
  double acc[4] = {0.0, 0.0, 0.0, 0.0};
  for (int ci = 0; ci < NC; ci++) {
    double wv[9];
    #pragma unroll
    for (int ky = 0; ky < 3; ky++) {
      int yy = y + ky - 1;
      #pragma unroll
      for (int kx = 0; kx < 3; kx++) {
        int xx = x + kx - 1;
        wv[ky * 3 + kx] = (yy >= 0 && yy < NH && xx >= 0 && xx < NW)
                          ? simg[ci * 256 + yy * 16 + xx] : 0.0;
      }
    }
    #pragma unroll
    for (int j = 0; j < 4; j++) {
      const float* wp = w + ((co0 + j) * NC + ci) * 9;  // uniform -> s_loads
      double a = acc[j];
      #pragma unroll
      for (int k = 0; k < 9; k++) a += wv[k] * (double)wp[k];
      acc[j] = a;
    }
  }
  double lsum = 0.0;
  #pragma unroll
  for (int j = 0; j < 4; j++) {
    int co = co0 + j;
    int i = co * 256 + tid;
    int gi = b * NC * NH * NW + i;
    double val = simg[i] * 0.5 + (acc[j] + (double)bias[co]) * 0.5;
    double zh = z_hat_d[gi] + val;
    z_hat_d[gi] = zh;
    out_zhat[gi] = (float)zh;
    z_res[gi] -= val;
    double df = zh - (double)z[gi];
    lsum += df * df;
  }
  __syncthreads();              // done with simg contents
  double* red = simg;           // reuse LDS for reduction (stay at 64 KB)
  red[tid] = lsum; __syncthreads();
  for (int s = 128; s > 0; s >>= 1) {
    if (tid < s) red[tid] += red[tid + s];
    __syncthreads();
  }
  if (tid == 0) atomicAdd(loss_d, red[0]);
}

__global__ void k_finalize(const double* __restrict__ loss_d, float* __restrict__ out_loss) {
  *out_loss = (float)(*loss_d * (1.25 / (5.0 * (double)NTOT)));
}

extern "C" void kernel_launch(void* const* d_in, const int* in_sizes, int n_in,
                              void* d_out, int out_size, void* d_ws, size_t ws_size,
                              hipStream_t stream) {
  const float* z     = (const float*)d_in[0];   // [64,32,16,16]
  const float* emb   = (const float*)d_in[1];   // [4096,32]
  const float* phi_w = (const float*)d_in[2];   // [4,32,32,3,3]
  const float* phi_b = (const float*)d_in[3];   // [4,32]

  float* out      = (float*)d_out;
  float* out_zhat = out;
  float* out_loss = out + NTOT;
  float* out_idx  = out + NTOT + 1; // [64,341] as floats

  double* ws      = (double*)d_ws;
  double* z_res   = ws;                    // 524288
  double* z_hat_d = z_res + NTOT;          // 524288
  double* q_small = z_hat_d + NTOT;        // 131072 (max nel for si<=3)
  double* t1      = q_small + 131072;      // 262144 (max B*C*16*8)
  double* q       = t1 + 262144;           // 524288
  double* r       = q + NTOT;              // 131072 (si<=3 only)
  double* emb_sq  = r + 131072;            // 4096
  double* loss_d  = emb_sq + NE;           // 1 (+7 pad)
  float* emb_t    = (float*)(loss_d + 8);  // 131072 floats
  int* idx_ws     = (int*)(emb_t + NE * NC); // 16384 ints

  k_init<<<(NTOT + 255) / 256, 256, 0, stream>>>(z, z_res, z_hat_d, loss_d);
  k_embsq<<<(NE + 255) / 256, 256, 0, stream>>>(emb, emb_sq);
  k_transpose<<<NE / 64, 256, 0, stream>>>(emb, emb_t);

  const int phs[5]  = {1, 2, 4, 8, 16};
  // Phi tick selection: ticks = np.linspace(1/12, 11/12, 4) in float64.
  // si=2 is an exact tie in real arithmetic, but f64 linspace rounding makes
  // |ticks[2]-0.5| smaller by 2 ulps -> pi=2 (verified by exact mantissa calc).
  const int pis[5]  = {0, 1, 2, 2, 3};
  const int offs[5] = {0, 1, 5, 21, 85};

  for (int si = 0; si < 5; si++) {
    int ph = phs[si];
    int nrows = NB * ph * ph;
    int nel = NB * NC * ph * ph;
    const double* rptr;
    if (si != 4) {
      int f = NH / ph;
      k_pool<<<(nel + 255) / 256, 256, 0, stream>>>(z_res, r, ph, f);
      rptr = r;
    } else {
      rptr = z_res;  // [B,C,16,16] layout matches ph=16
    }
    k_argmin<<<nrows / ROWS, 256, 0, stream>>>(rptr, emb_t, emb_sq, ph,
                                               idx_ws, out_idx, offs[si]);
    double* qdst = (si != 4) ? q_small : q;
    k_gather<<<(nel + 255) / 256, 256, 0, stream>>>(idx_ws, emb, qdst, ph);
    if (si != 4) {
      int nh = NB * NC * 16 * ph;
      k_bicubic_h<<<(nh + 255) / 256, 256, 0, stream>>>(q_small, t1, ph);
      k_bicubic_w<<<(NTOT + 255) / 256, 256, 0, stream>>>(t1, q, ph);
    }
    k_phi_update<<<NB * 8, 256, 0, stream>>>(q, phi_w + pis[si] * NC * NC * 9,
                                             phi_b + pis[si] * NC,
                                             z, z_hat_d, z_res, out_zhat, loss_d);
  }
  k_finalize<<<1, 1, 0, stream>>>(loss_d, out_loss);
}